// Round 15
// baseline (187.069 us; speedup 1.0000x reference)
//
#include <hip/hip_runtime.h>

#define NB 128
#define NC 12
#define NL 1024
#define NDIL 7
#define NDIV 2
#define NH 32
#define NK 8
#define NKSZ 9
#define NNCP 6
#define OUTPB (NDIL*NDIV*2*NH*NK)   // 7168

// LDS (f16): [Z0 256][g0 1024][Z1 256][g1 1024]...[g7 1024][Z8 256]
// zero strips shared between adjacent waves' pads; strips only ever hold zeros.
#define SER16 1280
#define NWAVES 8
#define LDS_F16 (NWAVES*SER16 + 256)   // 10496 f16 = 20992 B

typedef __fp16 h2 __attribute__((ext_vector_type(2)));

__device__ __forceinline__ float4 ld4(const float* p) { return *(const float4*)p; }

__device__ __forceinline__ float sgpr_f(float v) {
    return __int_as_float(__builtin_amdgcn_readfirstlane(__float_as_int(v)));
}
__device__ __forceinline__ h2 pkrtz(float x, float y) {
    return __builtin_amdgcn_cvt_pkrtz(x, y);
}
__device__ __forceinline__ h2 ldh2(const __fp16* p) {
    return __builtin_bit_cast(h2, *(const unsigned*)(p));
}

template<int CTRL, int RM>
__device__ __forceinline__ float dppadd_f(float x) {
    int t = __builtin_amdgcn_update_dpp(0, __float_as_int(x), CTRL, RM, 0xf, false);
    return x + __int_as_float(t);
}
template<int CTRL, int RM>
__device__ __forceinline__ unsigned dppadd_u(unsigned x) {
    int t = __builtin_amdgcn_update_dpp(0, (int)x, CTRL, RM, 0xf, false);
    return x + (unsigned)t;
}
// full-wave sum; result valid on lane 63
#define RSUM_F(x) { x = dppadd_f<0x111,0xf>(x); x = dppadd_f<0x112,0xf>(x); \
                    x = dppadd_f<0x114,0xf>(x); x = dppadd_f<0x118,0xf>(x); \
                    x = dppadd_f<0x142,0xa>(x); x = dppadd_f<0x143,0xc>(x); }
#define RSUM_U(x) { x = dppadd_u<0x111,0xf>(x); x = dppadd_u<0x112,0xf>(x); \
                    x = dppadd_u<0x114,0xf>(x); x = dppadd_u<0x118,0xf>(x); \
                    x = dppadd_u<0x142,0xa>(x); x = dppadd_u<0x143,0xc>(x); }

#define Wk(k,t) wf[(k)*NKSZ+(t)]

#define ARGBIN(A, OK)                                                     \
    {                                                                     \
        float mx = fmaxf(fmaxf(A[0], A[1]), A[2]);                        \
        mx = fmaxf(fmaxf(mx, A[3]), A[4]);                                \
        mx = fmaxf(fmaxf(mx, A[5]), A[6]);                                \
        mx = fmaxf(mx, A[7]);                                             \
        float mn = fminf(fminf(A[0], A[1]), A[2]);                        \
        mn = fminf(fminf(mn, A[3]), A[4]);                                \
        mn = fminf(fminf(mn, A[5]), A[6]);                                \
        mn = fminf(mn, A[7]);                                             \
        if (OK) {                                                         \
            _Pragma("unroll")                                             \
            for (int k = 0; k < NK; ++k) {                                \
                cm[k] += (A[k] == mx) ? A[k] : 0.f;                       \
                cn[k] += (A[k] == mn) ? 1u : 0u;                          \
            }                                                             \
        }                                                                 \
    }

// one 128-position chunk (2/lane); f16 data, f32 accumulate (fma_mix-eligible)
template<int D>
__device__ __forceinline__ void chunk_op(const __fp16* __restrict__ bp,
                                         const float (&wf)[NK*NKSZ], bool ok1,
                                         float (&cm)[NK], unsigned (&cn)[NK]) {
    float a0[NK], a1[NK];
    #pragma unroll
    for (int k = 0; k < NK; ++k) { a0[k] = 0.f; a1[k] = 0.f; }
    if constexpr (D == 1) {
        h2 q[5];
        #pragma unroll
        for (int i = 0; i < 5; ++i) q[i] = ldh2(bp + 2*i);
        #pragma unroll
        for (int t = 0; t < NKSZ; ++t) {
            const float v0 = (t & 1) ? (float)q[t>>1].y : (float)q[t>>1].x;
            const float v1 = (t & 1) ? (float)q[(t+1)>>1].x : (float)q[t>>1].y;
            #pragma unroll
            for (int k = 0; k < NK; ++k) {
                a0[k] = fmaf(Wk(k,t), v0, a0[k]);
                a1[k] = fmaf(Wk(k,t), v1, a1[k]);
            }
        }
    } else {
        h2 r[NKSZ];
        #pragma unroll
        for (int t = 0; t < NKSZ; ++t) r[t] = ldh2(bp + t*D);
        #pragma unroll
        for (int t = 0; t < NKSZ; ++t)
            #pragma unroll
            for (int k = 0; k < NK; ++k) {
                a0[k] = fmaf(Wk(k,t), (float)r[t].x, a0[k]);
                a1[k] = fmaf(Wk(k,t), (float)r[t].y, a1[k]);
            }
    }
    ARGBIN(a0, true);
    ARGBIN(a1, ok1);
}

// conv over 1024 positions: 7 rolled chunks + peeled last chunk (okl gate)
template<int D>
__device__ __forceinline__ void conv_body(const __fp16* __restrict__ bp0,
                                          const float (&wf)[NK*NKSZ], bool okl,
                                          float (&cm)[NK], unsigned (&cn)[NK]) {
    const __fp16* bp = (D == 1) ? (bp0 - 4) : (bp0 - 4*D);
    #pragma unroll 1
    for (int c = 0; c < 7; ++c, bp += 128)
        chunk_op<D>(bp, wf, true, cm, cn);
    chunk_op<D>(bp, wf, okl, cm, cn);
}

__global__ __launch_bounds__(512) void hydra_kernel(
    const float* __restrict__ X,   // [B, C, L]
    const float* __restrict__ W,   // [NDIL, NDIV, K*H, 1, KSZ]
    const int*   __restrict__ I,   // [NDIL, NDIV, H, NCP]
    float*       __restrict__ out) // [B, 28*H*K]
{
    __shared__ __fp16 lds16[LDS_F16];

    const int bid = blockIdx.x;
    const int h8 = bid & 3;              // 4 groups of 8 h-values
    const int dj = (bid >> 2) % 14;
    const int b  = (bid >> 2) / 14;
    const int di = dj >> 1;
    const int j  = dj & 1;

    const int tid  = threadIdx.x;
    const int lane = tid & 63;
    const int wid  = __builtin_amdgcn_readfirstlane(tid >> 6);   // 0..7
    const int h    = h8 * 8 + wid;        // wave-uniform
    const int Sw   = 256 + wid * SER16;   // this wave's series base (f16 units)

    // zero own pad strips (wid and wid+1); duplicates benign
    #pragma unroll
    for (int z = 0; z < 2; ++z) {
        uint2 zz; zz.x = 0u; zz.y = 0u;
        *(uint2*)(lds16 + (wid + z) * SER16 + 4 * lane) = zz;
    }

    // --- gather-sum into this wave's f16 series (wave-private, no barrier) -
    const int* idx = I + ((di*NDIV + j)*NH + h)*NNCP;
    const float* xb = X + (size_t)b * NC * NL;
    const float* p0 = xb + idx[0]*NL;
    const float* p1 = xb + idx[1]*NL;
    const float* p2 = xb + idx[2]*NL;
    const float* p3 = xb + idx[3]*NL;
    const float* p4 = xb + idx[4]*NL;
    const float* p5 = xb + idx[5]*NL;

    if (j == 0) {
        #pragma unroll
        for (int c = 0; c < 4; ++c) {
            const int e = 256*c + 4*lane;
            float4 v0 = ld4(p0+e), v1 = ld4(p1+e), v2 = ld4(p2+e);
            float4 v3 = ld4(p3+e), v4 = ld4(p4+e), v5 = ld4(p5+e);
            float4 s;
            s.x = v0.x+v1.x+v2.x+v3.x+v4.x+v5.x;
            s.y = v0.y+v1.y+v2.y+v3.y+v4.y+v5.y;
            s.z = v0.z+v1.z+v2.z+v3.z+v4.z+v5.z;
            s.w = v0.w+v1.w+v2.w+v3.w+v4.w+v5.w;
            uint2 pk;
            pk.x = __builtin_bit_cast(unsigned, pkrtz(s.x, s.y));
            pk.y = __builtin_bit_cast(unsigned, pkrtz(s.z, s.w));
            *(uint2*)(lds16 + Sw + e) = pk;
        }
    } else {
        // diff-of-gather == gather-of-diff (linearity)
        float4 sa[4];
        #pragma unroll
        for (int c = 0; c < 4; ++c) {
            const int e = 256*c + 4*lane;
            float4 v0 = ld4(p0+e), v1 = ld4(p1+e), v2 = ld4(p2+e);
            float4 v3 = ld4(p3+e), v4 = ld4(p4+e), v5 = ld4(p5+e);
            sa[c].x = v0.x+v1.x+v2.x+v3.x+v4.x+v5.x;
            sa[c].y = v0.y+v1.y+v2.y+v3.y+v4.y+v5.y;
            sa[c].z = v0.z+v1.z+v2.z+v3.z+v4.z+v5.z;
            sa[c].w = v0.w+v1.w+v2.w+v3.w+v4.w+v5.w;
        }
        #pragma unroll
        for (int c = 0; c < 4; ++c) {
            const float nxt = (c < 3) ? __shfl(sa[(c+1) & 3].x, 0, 64) : 0.f;
            const float sh  = __shfl_down(sa[c].x, 1, 64);
            const float Se4 = (lane == 63) ? nxt : sh;
            float4 df;
            df.x = sa[c].y - sa[c].x;
            df.y = sa[c].z - sa[c].y;
            df.z = sa[c].w - sa[c].z;
            df.w = Se4 - sa[c].w;
            if (c == 3 && lane == 63) df.w = 0.f;   // diff series: slot 1023 = 0
            const int e = 256*c + 4*lane;
            uint2 pk;
            pk.x = __builtin_bit_cast(unsigned, pkrtz(df.x, df.y));
            pk.y = __builtin_bit_cast(unsigned, pkrtz(df.z, df.w));
            *(uint2*)(lds16 + Sw + e) = pk;
        }
    }

    // --- weights: force into SGPRs (wave-uniform h) -----------------------
    float wf[NK*NKSZ];
    {
        const float* Wp = W + (size_t)((di*NDIV + j)*(NK*NH) + h*NK) * NKSZ;
        #pragma unroll
        for (int i = 0; i < 18; ++i) {
            float4 v = ld4(Wp + 4*i);
            wf[4*i+0] = sgpr_f(v.x); wf[4*i+1] = sgpr_f(v.y);
            wf[4*i+2] = sgpr_f(v.z); wf[4*i+3] = sgpr_f(v.w);
        }
    }

    float    cm[NK];
    unsigned cn[NK];
    #pragma unroll
    for (int k = 0; k < NK; ++k) { cm[k] = 0.f; cn[k] = 0u; }

    const __fp16* bp0 = lds16 + Sw + 2*lane;     // pos-pair base
    const bool    okl = (j == 0) || (lane != 63);

    switch (di) {
        case 0: conv_body<1>( bp0, wf, okl, cm, cn); break;
        case 1: conv_body<2>( bp0, wf, okl, cm, cn); break;
        case 2: conv_body<4>( bp0, wf, okl, cm, cn); break;
        case 3: conv_body<8>( bp0, wf, okl, cm, cn); break;
        case 4: conv_body<16>(bp0, wf, okl, cm, cn); break;
        case 5: conv_body<32>(bp0, wf, okl, cm, cn); break;
        default: conv_body<64>(bp0, wf, okl, cm, cn); break;
    }

    // pack counts (each half-word sum <= 1024, no carry crossing)
    unsigned cp[4];
    #pragma unroll
    for (int i = 0; i < 4; ++i) cp[i] = cn[2*i] | (cn[2*i+1] << 16);

    // DPP wave sums (VALU-only), results land on lane 63
    #pragma unroll
    for (int k = 0; k < NK; ++k) RSUM_F(cm[k]);
    #pragma unroll
    for (int i = 0; i < 4; ++i) RSUM_U(cp[i]);

    // lane 63 writes this wave's 16 outputs directly (no barrier, no LDS)
    if (lane == 63) {
        float* ob = out + (size_t)b*OUTPB + (dj*2)*(NH*NK) + h*NK;
        #pragma unroll
        for (int k = 0; k < NK; ++k) ob[k] = cm[k];
        float* oc = ob + NH*NK;
        #pragma unroll
        for (int i = 0; i < 4; ++i) {
            oc[2*i]     = (float)(cp[i] & 0xffffu);
            oc[2*i + 1] = (float)(cp[i] >> 16);
        }
    }
}

extern "C" void kernel_launch(void* const* d_in, const int* in_sizes, int n_in,
                              void* d_out, int out_size, void* d_ws, size_t ws_size,
                              hipStream_t stream) {
    const float* X = (const float*)d_in[0];
    const float* W = (const float*)d_in[1];
    const int*   I = (const int*)d_in[2];
    float* out = (float*)d_out;

    const int nblocks = NB * (NDIL*NDIV) * (NH/NWAVES);   // 128*14*4 = 7168
    hydra_kernel<<<dim3(nblocks), dim3(512), 0, stream>>>(X, W, I, out);
}

// Round 16
// 160.803 us; speedup vs baseline: 1.1633x; 1.1633x over previous
//
#include <hip/hip_runtime.h>

#define NB 128
#define NC 12
#define NL 1024
#define NDIL 7
#define NDIV 2
#define NH 32
#define NK 8
#define NKSZ 9
#define NNCP 6
#define OUTPB (NDIL*NDIV*2*NH*NK)   // 7168

// LDS: [Z0 256][g0 1024][Z1 256][g1 1024][Z2 256][g2 1024][Z3 256][g3 1024][Z4 256]
// zero strips shared between adjacent waves' pads; wave w zeroes strips w and w+1.
#define SER_STRIDE 1280
#define LDS_FLOATS (4*SER_STRIDE + 256)   // 5376 floats = 21504 B

__device__ __forceinline__ float4 ld4(const float* p) { return *(const float4*)p; }

__device__ __forceinline__ float sgpr_f(float v) {
    return __int_as_float(__builtin_amdgcn_readfirstlane(__float_as_int(v)));
}

// cn += (a == mn) in 2 VALU ops: compare into vcc, add carry bit.
__device__ __forceinline__ void cnt_eq(unsigned &cn, float a, float mn) {
    asm("v_cmp_eq_f32 vcc, %1, %2\n\t"
        "v_addc_co_u32 %0, vcc, 0, %0, vcc"
        : "+v"(cn) : "v"(a), "v"(mn) : "vcc");
}

template<int CTRL, int RM>
__device__ __forceinline__ float dppadd_f(float x) {
    int t = __builtin_amdgcn_update_dpp(0, __float_as_int(x), CTRL, RM, 0xf, false);
    return x + __int_as_float(t);
}
template<int CTRL, int RM>
__device__ __forceinline__ unsigned dppadd_u(unsigned x) {
    int t = __builtin_amdgcn_update_dpp(0, (int)x, CTRL, RM, 0xf, false);
    return x + (unsigned)t;
}
// full-wave sum; result valid on lane 63
#define RSUM_F(x) { x = dppadd_f<0x111,0xf>(x); x = dppadd_f<0x112,0xf>(x); \
                    x = dppadd_f<0x114,0xf>(x); x = dppadd_f<0x118,0xf>(x); \
                    x = dppadd_f<0x142,0xa>(x); x = dppadd_f<0x143,0xc>(x); }
#define RSUM_U(x) { x = dppadd_u<0x111,0xf>(x); x = dppadd_u<0x112,0xf>(x); \
                    x = dppadd_u<0x114,0xf>(x); x = dppadd_u<0x118,0xf>(x); \
                    x = dppadd_u<0x142,0xa>(x); x = dppadd_u<0x143,0xc>(x); }

#define Wk(k,t) wf[(k)*NKSZ+(t)]

#define ARGBIN(A, OK)                                                     \
    {                                                                     \
        float mx = fmaxf(fmaxf(A[0], A[1]), A[2]);                        \
        mx = fmaxf(fmaxf(mx, A[3]), A[4]);                                \
        mx = fmaxf(fmaxf(mx, A[5]), A[6]);                                \
        mx = fmaxf(mx, A[7]);                                             \
        float mn = fminf(fminf(A[0], A[1]), A[2]);                        \
        mn = fminf(fminf(mn, A[3]), A[4]);                                \
        mn = fminf(fminf(mn, A[5]), A[6]);                                \
        mn = fminf(mn, A[7]);                                             \
        if (OK) {                                                         \
            _Pragma("unroll")                                             \
            for (int k = 0; k < NK; ++k) {                                \
                cm[k] += (A[k] == mx) ? A[k] : 0.f;                       \
                cnt_eq(cn[k], A[k], mn);                                  \
            }                                                             \
        }                                                                 \
    }

// conv + argbin over 1024 positions (2/lane/chunk), compile-time dilation D.
// Rolled chunk loop (VGPR-friendly); tap offsets fold into ds_read immediates.
template<int D>
__device__ __forceinline__ void conv_body(const float* __restrict__ bp0,
                                          const float (&wf)[NK*NKSZ], bool okl,
                                          float (&cm)[NK], unsigned (&cn)[NK]) {
    if constexpr (D == 1) {
        const float* bp = bp0 - 4;
        for (int c = 0; c < 8; ++c, bp += 128) {
            float2 q0 = *(const float2*)(bp);
            float2 q1 = *(const float2*)(bp + 2);
            float2 q2 = *(const float2*)(bp + 4);
            float2 q3 = *(const float2*)(bp + 6);
            float2 q4 = *(const float2*)(bp + 8);
            const float win[10] = { q0.x,q0.y,q1.x,q1.y,q2.x,q2.y,q3.x,q3.y,q4.x,q4.y };
            float a0[NK], a1[NK];
            #pragma unroll
            for (int k = 0; k < NK; ++k) { a0[k] = 0.f; a1[k] = 0.f; }
            #pragma unroll
            for (int t = 0; t < NKSZ; ++t)
                #pragma unroll
                for (int k = 0; k < NK; ++k) {
                    a0[k] = fmaf(Wk(k,t), win[t],   a0[k]);
                    a1[k] = fmaf(Wk(k,t), win[t+1], a1[k]);
                }
            ARGBIN(a0, true);
            ARGBIN(a1, (c != 7) || okl);
        }
    } else {
        const float* bp = bp0 - 4*D;
        for (int c = 0; c < 8; ++c, bp += 128) {
            float2 r[NKSZ];
            #pragma unroll
            for (int t = 0; t < NKSZ; ++t)
                r[t] = *(const float2*)(bp + t*D);   // imm-foldable offsets
            float a0[NK], a1[NK];
            #pragma unroll
            for (int k = 0; k < NK; ++k) { a0[k] = 0.f; a1[k] = 0.f; }
            #pragma unroll
            for (int t = 0; t < NKSZ; ++t)
                #pragma unroll
                for (int k = 0; k < NK; ++k) {
                    a0[k] = fmaf(Wk(k,t), r[t].x, a0[k]);
                    a1[k] = fmaf(Wk(k,t), r[t].y, a1[k]);
                }
            ARGBIN(a0, true);
            ARGBIN(a1, (c != 7) || okl);
        }
    }
}

__global__ __launch_bounds__(256) void hydra_kernel(
    const float* __restrict__ X,   // [B, C, L]
    const float* __restrict__ W,   // [NDIL, NDIV, K*H, 1, KSZ]
    const int*   __restrict__ I,   // [NDIL, NDIV, H, NCP]
    float*       __restrict__ out) // [B, 28*H*K]
{
    __shared__ float lds[LDS_FLOATS];

    const int bid = blockIdx.x;
    const int h4 = bid & 7;
    const int dj = (bid >> 3) % 14;
    const int b  = (bid >> 3) / 14;
    const int di = dj >> 1;
    const int j  = dj & 1;

    const int tid  = threadIdx.x;
    const int lane = tid & 63;
    const int wid  = __builtin_amdgcn_readfirstlane(tid >> 6);
    const int h    = h4 * 4 + wid;            // wave-uniform
    const int Sw   = 256 + wid * SER_STRIDE;  // this wave's series base

    // zero own pad strips (w and w+1); neighbor duplicate zero-writes benign
    #pragma unroll
    for (int z = 0; z < 2; ++z) {
        float4 zz; zz.x = 0.f; zz.y = 0.f; zz.z = 0.f; zz.w = 0.f;
        *(float4*)(lds + (wid + z) * SER_STRIDE + 4 * lane) = zz;
    }

    // --- gather-sum into this wave's series (wave-private, no barrier) ----
    const int* idx = I + ((di*NDIV + j)*NH + h)*NNCP;
    const float* xb = X + (size_t)b * NC * NL;
    const float* p0 = xb + idx[0]*NL;
    const float* p1 = xb + idx[1]*NL;
    const float* p2 = xb + idx[2]*NL;
    const float* p3 = xb + idx[3]*NL;
    const float* p4 = xb + idx[4]*NL;
    const float* p5 = xb + idx[5]*NL;

    if (j == 0) {
        #pragma unroll
        for (int c = 0; c < 4; ++c) {
            const int e = 256*c + 4*lane;
            float4 v0 = ld4(p0+e), v1 = ld4(p1+e), v2 = ld4(p2+e);
            float4 v3 = ld4(p3+e), v4 = ld4(p4+e), v5 = ld4(p5+e);
            float4 s;
            s.x = v0.x+v1.x+v2.x+v3.x+v4.x+v5.x;
            s.y = v0.y+v1.y+v2.y+v3.y+v4.y+v5.y;
            s.z = v0.z+v1.z+v2.z+v3.z+v4.z+v5.z;
            s.w = v0.w+v1.w+v2.w+v3.w+v4.w+v5.w;
            *(float4*)(lds + Sw + e) = s;
        }
    } else {
        // diff-of-gather == gather-of-diff (linearity)
        float4 sa[4];
        #pragma unroll
        for (int c = 0; c < 4; ++c) {
            const int e = 256*c + 4*lane;
            float4 v0 = ld4(p0+e), v1 = ld4(p1+e), v2 = ld4(p2+e);
            float4 v3 = ld4(p3+e), v4 = ld4(p4+e), v5 = ld4(p5+e);
            sa[c].x = v0.x+v1.x+v2.x+v3.x+v4.x+v5.x;
            sa[c].y = v0.y+v1.y+v2.y+v3.y+v4.y+v5.y;
            sa[c].z = v0.z+v1.z+v2.z+v3.z+v4.z+v5.z;
            sa[c].w = v0.w+v1.w+v2.w+v3.w+v4.w+v5.w;
        }
        #pragma unroll
        for (int c = 0; c < 4; ++c) {
            const float nxt = (c < 3) ? __shfl(sa[(c+1) & 3].x, 0, 64) : 0.f;
            const float sh  = __shfl_down(sa[c].x, 1, 64);
            const float Se4 = (lane == 63) ? nxt : sh;
            float4 df;
            df.x = sa[c].y - sa[c].x;
            df.y = sa[c].z - sa[c].y;
            df.z = sa[c].w - sa[c].z;
            df.w = Se4 - sa[c].w;
            if (c == 3 && lane == 63) df.w = 0.f;   // diff series: slot 1023 = 0
            const int e = 256*c + 4*lane;
            *(float4*)(lds + Sw + e) = df;
        }
    }

    // --- weights: force into SGPRs (wave-uniform h) -----------------------
    float wf[NK*NKSZ];
    {
        const float* Wp = W + (size_t)((di*NDIV + j)*(NK*NH) + h*NK) * NKSZ;
        #pragma unroll
        for (int i = 0; i < 18; ++i) {
            float4 v = ld4(Wp + 4*i);
            wf[4*i+0] = sgpr_f(v.x); wf[4*i+1] = sgpr_f(v.y);
            wf[4*i+2] = sgpr_f(v.z); wf[4*i+3] = sgpr_f(v.w);
        }
    }

    float    cm[NK];
    unsigned cn[NK];
    #pragma unroll
    for (int k = 0; k < NK; ++k) { cm[k] = 0.f; cn[k] = 0u; }

    const float* bp0 = lds + Sw + 2*lane;        // pos-pair base
    const bool   okl = (j == 0) || (lane != 63); // only pos 1023/j=1 invalid

    switch (di) {
        case 0: conv_body<1>( bp0, wf, okl, cm, cn); break;
        case 1: conv_body<2>( bp0, wf, okl, cm, cn); break;
        case 2: conv_body<4>( bp0, wf, okl, cm, cn); break;
        case 3: conv_body<8>( bp0, wf, okl, cm, cn); break;
        case 4: conv_body<16>(bp0, wf, okl, cm, cn); break;
        case 5: conv_body<32>(bp0, wf, okl, cm, cn); break;
        default: conv_body<64>(bp0, wf, okl, cm, cn); break;
    }

    // pack counts (each half-word sum <= 1024, no carry crossing)
    unsigned cp[4];
    #pragma unroll
    for (int i = 0; i < 4; ++i) cp[i] = cn[2*i] | (cn[2*i+1] << 16);

    // DPP wave sums (VALU-only), results land on lane 63
    #pragma unroll
    for (int k = 0; k < NK; ++k) RSUM_F(cm[k]);
    #pragma unroll
    for (int i = 0; i < 4; ++i) RSUM_U(cp[i]);

    // lane 63 writes this wave's 16 outputs directly (no barrier, no LDS)
    if (lane == 63) {
        float* ob = out + (size_t)b*OUTPB + (dj*2)*(NH*NK) + h*NK;
        #pragma unroll
        for (int k = 0; k < NK; ++k) ob[k] = cm[k];
        float* oc = ob + NH*NK;
        #pragma unroll
        for (int i = 0; i < 4; ++i) {
            oc[2*i]     = (float)(cp[i] & 0xffffu);
            oc[2*i + 1] = (float)(cp[i] >> 16);
        }
    }
}

extern "C" void kernel_launch(void* const* d_in, const int* in_sizes, int n_in,
                              void* d_out, int out_size, void* d_ws, size_t ws_size,
                              hipStream_t stream) {
    const float* X = (const float*)d_in[0];
    const float* W = (const float*)d_in[1];
    const int*   I = (const int*)d_in[2];
    float* out = (float*)d_out;

    const int nblocks = NB * (NDIL*NDIV) * (NH/4);   // 14336
    hydra_kernel<<<dim3(nblocks), dim3(256), 0, stream>>>(X, W, I, out);
}